// Round 3
// baseline (479.799 us; speedup 1.0000x reference)
//
#include <hip/hip_runtime.h>

// Problem constants (match reference)
#define BB 64
#define MM 2048
#define DD 512
#define CHUNK 64                 // rows of M handled per block
#define SPLITS (MM / CHUNK)      // 32 blocks per batch row

// Fused kernel: per (b, chunk) block computes the max-squared-distance row
// of its chunk, atomicMax-merges a packed (dist_bits<<32 | ~idx) into
// ws_best[b] (device-scope), and the LAST block for each b decodes the
// winner and gathers the row to out. One dispatch, no partials round-trip.
//
// Packing correctness: dists are >= 0, so IEEE bit pattern order == float
// order. ~idx in the low 32 bits makes equal-dist ties pick the SMALLER
// index under max, matching jnp.argmax first-occurrence semantics.
__global__ __launch_bounds__(256) void knn_fused_kernel(
    const float* __restrict__ inputs,            // [B, D]
    const float* __restrict__ buffer,            // [B, M, D]
    unsigned long long* __restrict__ ws_best,    // [B]
    unsigned int* __restrict__ ws_cnt,           // [B]
    float* __restrict__ out)                     // [B, D]
{
    const int b     = blockIdx.x;
    const int chunk = blockIdx.y;
    const int tid   = threadIdx.x;
    const int lane  = tid & 63;
    const int wave  = tid >> 6;
    const int g     = lane >> 4;   // 16-lane group = row within pass
    const int j     = lane & 15;   // lane within group

    // Query slice: lane covers float4 positions j, j+16, ..., j+112
    const float4* q4 = (const float4*)(inputs + (size_t)b * DD);
    float4 q[8];
    #pragma unroll
    for (int k = 0; k < 8; k++) q[k] = q4[j + k * 16];

    const float* base =
        buffer + (size_t)b * MM * DD + (size_t)chunk * CHUNK * DD;

    float best_d = -1.0f;
    int   best_i = 0;

    #pragma unroll
    for (int p = 0; p < 4; p++) {
        const int r = wave * 16 + p * 4 + g;            // increasing in p
        const float4* row4 = (const float4*)(base + (size_t)r * DD);
        float s = 0.0f;
        #pragma unroll
        for (int k = 0; k < 8; k++) {
            float4 v = row4[j + k * 16];
            float dx;
            dx = v.x - q[k].x; s = fmaf(dx, dx, s);
            dx = v.y - q[k].y; s = fmaf(dx, dx, s);
            dx = v.z - q[k].z; s = fmaf(dx, dx, s);
            dx = v.w - q[k].w; s = fmaf(dx, dx, s);
        }
        // butterfly sum within each 16-lane group (4 rows reduced at once)
        #pragma unroll
        for (int off = 1; off < 16; off <<= 1)
            s += __shfl_xor(s, off, 64);
        if (s > best_d) { best_d = s; best_i = r; }   // strict > => first occurrence
    }

    // cross-group argmax within the wave; tie -> lower index
    #pragma unroll
    for (int off = 16; off < 64; off <<= 1) {
        float od = __shfl_xor(best_d, off, 64);
        int   oi = __shfl_xor(best_i, off, 64);
        if (od > best_d || (od == best_d && oi < best_i)) {
            best_d = od; best_i = oi;
        }
    }

    __shared__ float sd[4];
    __shared__ int   si[4];
    __shared__ int   s_gather;   // -1 = not last block; else winning idx
    if (lane == 0) { sd[wave] = best_d; si[wave] = best_i; }
    __syncthreads();

    if (tid == 0) {
        float bd = sd[0]; int bi = si[0];
        #pragma unroll
        for (int w = 1; w < 4; w++) {
            if (sd[w] > bd || (sd[w] == bd && si[w] < bi)) { bd = sd[w]; bi = si[w]; }
        }
        const unsigned gidx = (unsigned)(chunk * CHUNK + bi);
        const unsigned long long pack =
            ((unsigned long long)__float_as_uint(bd) << 32) | (0xFFFFFFFFu - gidx);
        atomicMax(ws_best + b, pack);          // device-scope
        __threadfence();                        // publish before counting in
        const unsigned prev = atomicAdd(ws_cnt + b, 1u);
        if (prev == SPLITS - 1) {
            // all 32 blocks for this b have merged; read final value
            const unsigned long long v = atomicMax(ws_best + b, 0ULL);
            s_gather = (int)(0xFFFFFFFFu - (unsigned)(v & 0xFFFFFFFFu));
        } else {
            s_gather = -1;
        }
    }
    __syncthreads();

    const int idx = s_gather;
    if (idx >= 0 && tid < 128) {
        const float4* src = (const float4*)(buffer + ((size_t)b * MM + idx) * DD);
        float4*       dst = (float4*)(out + (size_t)b * DD);
        dst[tid] = src[tid];   // 128 float4s = 2 KiB row
    }
}

extern "C" void kernel_launch(void* const* d_in, const int* in_sizes, int n_in,
                              void* d_out, int out_size, void* d_ws, size_t ws_size,
                              hipStream_t stream) {
    const float* inputs = (const float*)d_in[0];   // [B, D]
    const float* buffer = (const float*)d_in[1];   // [B, M, D]
    float* out = (float*)d_out;                    // [B, D]

    unsigned long long* ws_best = (unsigned long long*)d_ws;       // [B]
    unsigned int*       ws_cnt  = (unsigned int*)(ws_best + BB);   // [B]

    // ws is poisoned to 0xAA each call — zero the 768 B we use (capturable).
    hipMemsetAsync(d_ws, 0, BB * sizeof(unsigned long long) + BB * sizeof(unsigned int),
                   stream);

    dim3 grid(BB, SPLITS);
    knn_fused_kernel<<<grid, 256, 0, stream>>>(inputs, buffer, ws_best, ws_cnt, out);
}

// Round 4
// 375.745 us; speedup vs baseline: 1.2769x; 1.2769x over previous
//
#include <hip/hip_runtime.h>

// Problem constants (match reference)
#define BB 64
#define MM 2048
#define DD 512
#define CHUNK 64                 // rows of M handled per block
#define SPLITS (MM / CHUNK)      // 32 partials per batch row

// Kernel 1: per (b, chunk) block, argmax of squared distance over 64 rows.
// 256 threads = 4 waves; each wave owns 16 rows, processed 4 rows per pass.
// Memory layout: every wave-load is a fully-contiguous 1 KiB (64 lanes x
// float4) slab — one VMEM request per instruction (vs 4 segments in the
// previous 16-lane-group layout). 8 independent loads in flight per pass,
// and the four 6-step butterfly reductions are independent chains that
// pipeline instead of serializing.
__global__ __launch_bounds__(256) void dist_argmax_kernel(
    const float* __restrict__ inputs,   // [B, D]
    const float* __restrict__ buffer,   // [B, M, D]
    float* __restrict__ ws_d,           // [B, SPLITS]
    int*   __restrict__ ws_i)           // [B, SPLITS]
{
    const int b     = blockIdx.x;
    const int chunk = blockIdx.y;
    const int tid   = threadIdx.x;
    const int lane  = tid & 63;
    const int wave  = tid >> 6;

    // Query: lane covers float4 #lane (bytes 0..1023) and #lane+64
    const float4* q4 = (const float4*)(inputs + (size_t)b * DD);
    const float4 q0 = q4[lane];
    const float4 q1 = q4[lane + 64];

    const float4* base4 =
        (const float4*)(buffer + (size_t)b * MM * DD + (size_t)chunk * CHUNK * DD);

    float best_d = -1.0f;
    int   best_i = 0;

    #pragma unroll
    for (int p = 0; p < 4; p++) {
        const int r = wave * 16 + p * 4;               // rows r..r+3, increasing
        const float4* row = base4 + (size_t)r * (DD / 4);
        // 8 independent contiguous 1-KiB wave loads (rows r..r+3)
        float4 a0 = row[lane];        float4 b0 = row[lane + 64];
        float4 a1 = row[lane + 128];  float4 b1 = row[lane + 192];
        float4 a2 = row[lane + 256];  float4 b2 = row[lane + 320];
        float4 a3 = row[lane + 384];  float4 b3 = row[lane + 448];

        float s0 = 0.f, s1 = 0.f, s2 = 0.f, s3 = 0.f, dx;
        dx = a0.x - q0.x; s0 = fmaf(dx, dx, s0);
        dx = a0.y - q0.y; s0 = fmaf(dx, dx, s0);
        dx = a0.z - q0.z; s0 = fmaf(dx, dx, s0);
        dx = a0.w - q0.w; s0 = fmaf(dx, dx, s0);
        dx = b0.x - q1.x; s0 = fmaf(dx, dx, s0);
        dx = b0.y - q1.y; s0 = fmaf(dx, dx, s0);
        dx = b0.z - q1.z; s0 = fmaf(dx, dx, s0);
        dx = b0.w - q1.w; s0 = fmaf(dx, dx, s0);

        dx = a1.x - q0.x; s1 = fmaf(dx, dx, s1);
        dx = a1.y - q0.y; s1 = fmaf(dx, dx, s1);
        dx = a1.z - q0.z; s1 = fmaf(dx, dx, s1);
        dx = a1.w - q0.w; s1 = fmaf(dx, dx, s1);
        dx = b1.x - q1.x; s1 = fmaf(dx, dx, s1);
        dx = b1.y - q1.y; s1 = fmaf(dx, dx, s1);
        dx = b1.z - q1.z; s1 = fmaf(dx, dx, s1);
        dx = b1.w - q1.w; s1 = fmaf(dx, dx, s1);

        dx = a2.x - q0.x; s2 = fmaf(dx, dx, s2);
        dx = a2.y - q0.y; s2 = fmaf(dx, dx, s2);
        dx = a2.z - q0.z; s2 = fmaf(dx, dx, s2);
        dx = a2.w - q0.w; s2 = fmaf(dx, dx, s2);
        dx = b2.x - q1.x; s2 = fmaf(dx, dx, s2);
        dx = b2.y - q1.y; s2 = fmaf(dx, dx, s2);
        dx = b2.z - q1.z; s2 = fmaf(dx, dx, s2);
        dx = b2.w - q1.w; s2 = fmaf(dx, dx, s2);

        dx = a3.x - q0.x; s3 = fmaf(dx, dx, s3);
        dx = a3.y - q0.y; s3 = fmaf(dx, dx, s3);
        dx = a3.z - q0.z; s3 = fmaf(dx, dx, s3);
        dx = a3.w - q0.w; s3 = fmaf(dx, dx, s3);
        dx = b3.x - q1.x; s3 = fmaf(dx, dx, s3);
        dx = b3.y - q1.y; s3 = fmaf(dx, dx, s3);
        dx = b3.z - q1.z; s3 = fmaf(dx, dx, s3);
        dx = b3.w - q1.w; s3 = fmaf(dx, dx, s3);

        // four independent 6-step butterflies — chains pipeline
        #pragma unroll
        for (int off = 1; off < 64; off <<= 1) {
            s0 += __shfl_xor(s0, off, 64);
            s1 += __shfl_xor(s1, off, 64);
            s2 += __shfl_xor(s2, off, 64);
            s3 += __shfl_xor(s3, off, 64);
        }
        // rows visited in increasing index order; strict > = first occurrence
        if (s0 > best_d) { best_d = s0; best_i = r; }
        if (s1 > best_d) { best_d = s1; best_i = r + 1; }
        if (s2 > best_d) { best_d = s2; best_i = r + 2; }
        if (s3 > best_d) { best_d = s3; best_i = r + 3; }
    }

    __shared__ float sd[4];
    __shared__ int   si[4];
    if (lane == 0) { sd[wave] = best_d; si[wave] = best_i; }
    __syncthreads();
    if (tid == 0) {
        float bd = sd[0]; int bi = si[0];
        #pragma unroll
        for (int w = 1; w < 4; w++) {
            if (sd[w] > bd || (sd[w] == bd && si[w] < bi)) { bd = sd[w]; bi = si[w]; }
        }
        ws_d[b * SPLITS + chunk] = bd;
        ws_i[b * SPLITS + chunk] = chunk * CHUNK + bi;
    }
}

// Kernel 2: reduce the 32 partials per batch row, gather the winning row.
__global__ __launch_bounds__(128) void gather_kernel(
    const float* __restrict__ ws_d,
    const int*   __restrict__ ws_i,
    const float* __restrict__ buffer,
    float*       __restrict__ out)
{
    const int b   = blockIdx.x;
    const int tid = threadIdx.x;
    __shared__ int s_idx;

    if (tid < 64) {
        float d = (tid < SPLITS) ? ws_d[b * SPLITS + tid] : -1.0f;
        int   i = (tid < SPLITS) ? ws_i[b * SPLITS + tid] : 0x7fffffff;
        #pragma unroll
        for (int off = 32; off > 0; off >>= 1) {
            float od = __shfl_down(d, off, 64);
            int   oi = __shfl_down(i, off, 64);
            if (od > d || (od == d && oi < i)) { d = od; i = oi; }
        }
        if (tid == 0) s_idx = i;
    }
    __syncthreads();

    const int idx = s_idx;
    const float4* src = (const float4*)(buffer + ((size_t)b * MM + idx) * DD);
    float4*       dst = (float4*)(out + (size_t)b * DD);
    dst[tid] = src[tid];   // D/4 = 128 float4s, 128 threads
}

extern "C" void kernel_launch(void* const* d_in, const int* in_sizes, int n_in,
                              void* d_out, int out_size, void* d_ws, size_t ws_size,
                              hipStream_t stream) {
    const float* inputs = (const float*)d_in[0];   // [B, D]
    const float* buffer = (const float*)d_in[1];   // [B, M, D]
    float* out  = (float*)d_out;                   // [B, D]
    float* ws_d = (float*)d_ws;                    // [B, SPLITS]
    int*   ws_i = (int*)(ws_d + BB * SPLITS);      // [B, SPLITS]

    dim3 grid(BB, SPLITS);
    dist_argmax_kernel<<<grid, 256, 0, stream>>>(inputs, buffer, ws_d, ws_i);
    gather_kernel<<<BB, 128, 0, stream>>>(ws_d, ws_i, buffer, out);
}

// Round 5
// 374.569 us; speedup vs baseline: 1.2809x; 1.0031x over previous
//
#include <hip/hip_runtime.h>
#include <stdint.h>

// Problem constants (match reference)
#define BB 64
#define MM 2048
#define DD 512
#define CHUNK 64                       // rows of M per block
#define SPLITS (MM / CHUNK)            // 32
#define TROWS 8                        // rows per LDS tile
#define NT (CHUNK / TROWS)             // 8 tiles per block
#define TILE_FLOATS (TROWS * DD)       // 4096 floats = 16 KiB
#define TILE_BYTES (TILE_FLOATS * 4)   // 16384

// Async global->LDS, 16B per lane (global_load_lds_dwordx4).
// LDS dest per lane MUST be wave-uniform-base + lane*16 (m104/m108) — our
// linear tid*16 layout satisfies this (no padding).
__device__ __forceinline__ void async_copy16(const void* g, void* l) {
    __builtin_amdgcn_global_load_lds(
        (const __attribute__((address_space(1))) unsigned int*)g,
        (__attribute__((address_space(3))) unsigned int*)l, 16, 0, 0);
}

// Kernel 1: per (b, chunk) block, argmax of squared L2 distance over 64 rows.
// Structure: double-buffered LDS pipeline. stage(t+1) is issued AFTER the
// barrier that publishes tile t, so its loads stay in flight across
// compute(t) — the global stream never waits on the reduction chains.
// Compute: 256 threads over an 8-row tile = 32 threads/row; each thread
// accumulates a 16-float strip in registers, then ONE 5-step butterfly per
// tile reduces all 8 rows at once (rows live in disjoint 32-lane halves).
__global__ __launch_bounds__(256) void dist_argmax_kernel(
    const float* __restrict__ inputs,   // [B, D]
    const float* __restrict__ buffer,   // [B, M, D]
    float* __restrict__ ws_d,           // [B, SPLITS]
    int*   __restrict__ ws_i)           // [B, SPLITS]
{
    __shared__ float lds[2 * TILE_FLOATS];   // 32 KiB -> 4 blocks/CU
    __shared__ float sd[4];
    __shared__ int   si[4];

    const int b     = blockIdx.x;
    const int chunk = blockIdx.y;
    const int tid   = threadIdx.x;
    const int lane  = tid & 63;
    const int wave  = tid >> 6;
    const int c     = tid & 31;   // column strip 0..31 (16 floats each)
    const int rit   = tid >> 5;   // row within tile 0..7

    // Query strip for this thread's columns: floats [c*16, c*16+16)
    const float4* q4 = (const float4*)(inputs + (size_t)b * DD + (size_t)c * 16);
    float4 q[4];
    #pragma unroll
    for (int k = 0; k < 4; k++) q[k] = q4[k];

    const char* gbase = (const char*)(buffer + (size_t)b * MM * DD
                                             + (size_t)chunk * CHUNK * DD);
    char* lbase = (char*)lds;

    // stage tile 0 into buffer 0
    #pragma unroll
    for (int i = 0; i < 4; i++)
        async_copy16(gbase + (size_t)i * 4096 + (size_t)tid * 16,
                     lbase + (size_t)i * 4096 + (size_t)tid * 16);

    float best_d = -1.0f;
    int   best_i = 0;

    for (int t = 0; t < NT; t++) {
        // Drains vmcnt(0): tile t is in LDS; everyone is past compute(t-1),
        // so buffer (t+1)&1 is free to overwrite.
        __syncthreads();

        if (t + 1 < NT) {
            const char* g = gbase + (size_t)(t + 1) * TILE_BYTES;
            char*       l = lbase + (size_t)((t + 1) & 1) * TILE_BYTES;
            #pragma unroll
            for (int i = 0; i < 4; i++)
                async_copy16(g + (size_t)i * 4096 + (size_t)tid * 16,
                             l + (size_t)i * 4096 + (size_t)tid * 16);
            // in flight across compute(t); drained by next iteration's barrier
        }

        // compute tile t (reads buffer t&1 only — disjoint from the prefetch)
        const float* L = lds + (size_t)(t & 1) * TILE_FLOATS
                             + (size_t)rit * DD + (size_t)c * 16;
        float s = 0.0f;
        #pragma unroll
        for (int k0 = 0; k0 < 4; k0++) {
            const int k = (k0 + (c >> 1)) & 3;   // bank stagger; covers k 0..3
            float4 v = *(const float4*)(L + k * 4);
            float dx;
            dx = v.x - q[k].x; s = fmaf(dx, dx, s);
            dx = v.y - q[k].y; s = fmaf(dx, dx, s);
            dx = v.z - q[k].z; s = fmaf(dx, dx, s);
            dx = v.w - q[k].w; s = fmaf(dx, dx, s);
        }
        // one butterfly reduces all 8 rows: each row occupies a 32-lane half
        #pragma unroll
        for (int off = 1; off < 32; off <<= 1)
            s += __shfl_xor(s, off, 64);

        // per-lane row sequence is ascending in t; strict > = first occurrence
        const int r = chunk * CHUNK + t * TROWS + rit;
        if (s > best_d) { best_d = s; best_i = r; }
    }

    // merge the two 32-lane halves of the wave (tie -> lower index)
    {
        float od = __shfl_xor(best_d, 32, 64);
        int   oi = __shfl_xor(best_i, 32, 64);
        if (od > best_d || (od == best_d && oi < best_i)) {
            best_d = od; best_i = oi;
        }
    }
    if (lane == 0) { sd[wave] = best_d; si[wave] = best_i; }
    __syncthreads();
    if (tid == 0) {
        float bd = sd[0]; int bi = si[0];
        #pragma unroll
        for (int w = 1; w < 4; w++) {
            if (sd[w] > bd || (sd[w] == bd && si[w] < bi)) { bd = sd[w]; bi = si[w]; }
        }
        ws_d[b * SPLITS + chunk] = bd;
        ws_i[b * SPLITS + chunk] = bi;
    }
}

// Kernel 2: reduce the 32 partials per batch row, gather the winning row.
__global__ __launch_bounds__(128) void gather_kernel(
    const float* __restrict__ ws_d,
    const int*   __restrict__ ws_i,
    const float* __restrict__ buffer,
    float*       __restrict__ out)
{
    const int b   = blockIdx.x;
    const int tid = threadIdx.x;
    __shared__ int s_idx;

    if (tid < 64) {
        float d = (tid < SPLITS) ? ws_d[b * SPLITS + tid] : -1.0f;
        int   i = (tid < SPLITS) ? ws_i[b * SPLITS + tid] : 0x7fffffff;
        #pragma unroll
        for (int off = 32; off > 0; off >>= 1) {
            float od = __shfl_down(d, off, 64);
            int   oi = __shfl_down(i, off, 64);
            if (od > d || (od == d && oi < i)) { d = od; i = oi; }
        }
        if (tid == 0) s_idx = i;
    }
    __syncthreads();

    const int idx = s_idx;
    const float4* src = (const float4*)(buffer + ((size_t)b * MM + idx) * DD);
    float4*       dst = (float4*)(out + (size_t)b * DD);
    dst[tid] = src[tid];   // D/4 = 128 float4s, 128 threads
}

extern "C" void kernel_launch(void* const* d_in, const int* in_sizes, int n_in,
                              void* d_out, int out_size, void* d_ws, size_t ws_size,
                              hipStream_t stream) {
    const float* inputs = (const float*)d_in[0];   // [B, D]
    const float* buffer = (const float*)d_in[1];   // [B, M, D]
    float* out  = (float*)d_out;                   // [B, D]
    float* ws_d = (float*)d_ws;                    // [B, SPLITS]
    int*   ws_i = (int*)(ws_d + BB * SPLITS);      // [B, SPLITS]

    dim3 grid(BB, SPLITS);
    dist_argmax_kernel<<<grid, 256, 0, stream>>>(inputs, buffer, ws_d, ws_i);
    gather_kernel<<<BB, 128, 0, stream>>>(ws_d, ws_i, buffer, out);
}